// Round 1
// baseline (2237.281 us; speedup 1.0000x reference)
//
#include <hip/hip_runtime.h>
#include <stdint.h>

#define N_IN  128
#define N_H   256
#define N_OUT 64

// ---------------- Threefry-2x32 (JAX-compatible) ----------------
__device__ __forceinline__ void tf4(uint32_t& x0, uint32_t& x1,
                                    const int r0, const int r1, const int r2, const int r3) {
  x0 += x1; x1 = (x1 << r0) | (x1 >> (32 - r0)); x1 ^= x0;
  x0 += x1; x1 = (x1 << r1) | (x1 >> (32 - r1)); x1 ^= x0;
  x0 += x1; x1 = (x1 << r2) | (x1 >> (32 - r2)); x1 ^= x0;
  x0 += x1; x1 = (x1 << r3) | (x1 >> (32 - r3)); x1 ^= x0;
}

__device__ __forceinline__ uint2 threefry2x32(uint32_t k0, uint32_t k1, uint32_t x0, uint32_t x1) {
  const uint32_t k2 = k0 ^ k1 ^ 0x1BD11BDAu;
  x0 += k0; x1 += k1;
  tf4(x0, x1, 13, 15, 26, 6);   x0 += k1; x1 += k2 + 1u;
  tf4(x0, x1, 17, 29, 16, 24);  x0 += k2; x1 += k0 + 2u;
  tf4(x0, x1, 13, 15, 26, 6);   x0 += k0; x1 += k1 + 3u;
  tf4(x0, x1, 17, 29, 16, 24);  x0 += k1; x1 += k2 + 4u;
  tf4(x0, x1, 13, 15, 26, 6);   x0 += k2; x1 += k0 + 5u;
  return make_uint2(x0, x1);
}

// dropout keep mask for flat index idx, matching
// jax.random.bernoulli(jax.random.key(42), 0.5, (N, 256))
// VARIANT 0: partitionable path (default True in recent JAX): bits = o.x ^ o.y, ctr=(0, idx)
// VARIANT 1: original path: idx<half -> o.x of (idx, idx+half); else o.y of (idx-half, idx)
#ifndef DROP_VARIANT
#define DROP_VARIANT 0
#endif

__device__ __forceinline__ bool drop_keep(uint32_t idx, uint32_t total) {
  uint32_t bits;
#if DROP_VARIANT == 0
  uint2 o = threefry2x32(0u, 42u, 0u, idx);
  bits = o.x ^ o.y;
#else
  uint32_t half = total >> 1;
  if (idx < half) { uint2 o = threefry2x32(0u, 42u, idx, idx + half); bits = o.x; }
  else            { uint2 o = threefry2x32(0u, 42u, idx - half, idx); bits = o.y; }
#endif
  // keep <=> uniform([bits]) < 0.5 <=> mantissa-topbit clear <=> bit31(bits)==0
  return (bits & 0x80000000u) == 0u;
}

// ---------------- edge-index layout detection ----------------
// If edge_index arrived as int64 (viewed as int32 pairs: low,high), all "high"
// words are 0 (node ids < 50000). For genuine int32 data the odd slots are
// random node ids (P(all zero) ~ 0). flag = element stride: 1 (int32) or 2 (int64).
__global__ void k_detect(const int* __restrict__ e, int E, int* __restrict__ flag) {
  __shared__ int s_nz;
  if (threadIdx.x == 0) s_nz = 0;
  __syncthreads();
  int n = E < 2048 ? E : 2048;
  for (int i = threadIdx.x; i < n; i += 256)
    if (e[2 * i + 1] != 0) atomicAdd(&s_nz, 1);
  __syncthreads();
  if (threadIdx.x == 0) *flag = (s_nz == 0) ? 2 : 1;
}

// ---------------- degree + norm ----------------
__global__ void k_deg(const int* __restrict__ eidx, float* __restrict__ deg, int E,
                      const int* __restrict__ flag) {
  int e = blockIdx.x * 256 + threadIdx.x;
  if (e >= E) return;
  int stride = *flag;
  int d = eidx[(size_t)(E + e) * stride];
  atomicAdd(deg + d, 1.0f);
}

__global__ void k_norm(const float* __restrict__ deg, float* __restrict__ norm, int N) {
  int i = blockIdx.x * 256 + threadIdx.x;
  if (i < N) { float d = deg[i]; norm[i] = d > 0.f ? rsqrtf(d) : 1.0f; }
}

// ---------------- layer-1 scatter: agg1[dst] += h[src]*norm[src] ----------------
__global__ void k_scatter1(const float* __restrict__ h, const float* __restrict__ norm,
                           const int* __restrict__ eidx, float* __restrict__ agg, int E,
                           const int* __restrict__ flag) {
  long long t = (long long)blockIdx.x * 256 + threadIdx.x;
  int e = (int)(t >> 5);
  if (e >= E) return;
  int lane = (int)(t & 31);
  int stride = *flag;
  int s = eidx[(size_t)e * stride];
  int d = eidx[(size_t)(E + e) * stride];
  float ns = norm[s];
  float4 v = reinterpret_cast<const float4*>(h + (size_t)s * N_IN)[lane];
  float* o = agg + (size_t)d * N_IN + lane * 4;
  atomicAdd(o + 0, v.x * ns);
  atomicAdd(o + 1, v.y * ns);
  atomicAdd(o + 2, v.z * ns);
  atomicAdd(o + 3, v.w * ns);
}

// ---------------- GEMM1 fused: h1s = dropout(relu((agg1@W1)*norm + b1)) * norm ----------------
// A [N,128] @ W [128,256]; 64x64 tile per block, 256 threads, 4x4 per thread.
__global__ __launch_bounds__(256) void k_gemm1(
    const float* __restrict__ A, const float* __restrict__ W, const float* __restrict__ b,
    const float* __restrict__ norm, float* __restrict__ Hout, int N) {
  __shared__ float As[64][129];   // +1 pad: column reads hit distinct banks
  __shared__ float Bs[128 * 64];
  const int tid = threadIdx.x;
  const int bx = blockIdx.x;      // col tile: 0..3
  const int by = blockIdx.y;      // row tile
  const int row0 = by * 64;

  // stage A tile (64 x 128)
#pragma unroll
  for (int i = 0; i < 8; i++) {
    int slot = tid + i * 256;       // 2048 float4 slots
    int r = slot >> 5, c4 = slot & 31;
    float4 v = make_float4(0.f, 0.f, 0.f, 0.f);
    if (row0 + r < N) v = reinterpret_cast<const float4*>(A + (size_t)(row0 + r) * N_IN)[c4];
    As[r][c4 * 4 + 0] = v.x; As[r][c4 * 4 + 1] = v.y;
    As[r][c4 * 4 + 2] = v.z; As[r][c4 * 4 + 3] = v.w;
  }
  // stage W tile (128 x 64)
#pragma unroll
  for (int i = 0; i < 8; i++) {
    int slot = tid + i * 256;       // 16 float4 per k-row
    int k = slot >> 4, c4 = slot & 15;
    reinterpret_cast<float4*>(Bs)[slot] =
        reinterpret_cast<const float4*>(W + (size_t)k * N_H + bx * 64)[c4];
  }
  __syncthreads();

  const int tx = tid & 15, ty = tid >> 4;
  float acc[4][4] = {};
#pragma unroll 2
  for (int k = 0; k < 128; k++) {
    float a[4];
#pragma unroll
    for (int i = 0; i < 4; i++) a[i] = As[ty * 4 + i][k];
    float4 bv = *reinterpret_cast<const float4*>(Bs + k * 64 + tx * 4);
    float bb[4] = {bv.x, bv.y, bv.z, bv.w};
#pragma unroll
    for (int i = 0; i < 4; i++)
#pragma unroll
      for (int j = 0; j < 4; j++) acc[i][j] = fmaf(a[i], bb[j], acc[i][j]);
  }

  const int c0 = bx * 64 + tx * 4;
  const uint32_t total = (uint32_t)N * N_H;
#pragma unroll
  for (int i = 0; i < 4; i++) {
    int r = row0 + ty * 4 + i;
    if (r >= N) break;
    float nr = norm[r];
    float ov[4];
#pragma unroll
    for (int j = 0; j < 4; j++) {
      float v = acc[i][j] * nr + b[c0 + j];
      v = fmaxf(v, 0.f);
      uint32_t idx = (uint32_t)r * N_H + (uint32_t)(c0 + j);
      v = drop_keep(idx, total) ? v * 2.0f : 0.f;
      ov[j] = v * nr;   // pre-apply src norm for layer 2
    }
    *reinterpret_cast<float4*>(Hout + (size_t)r * N_H + c0) =
        make_float4(ov[0], ov[1], ov[2], ov[3]);
  }
}

// ---------------- GEMM2: z = h1s @ W2  ([N,256] @ [256,64]) ----------------
__global__ __launch_bounds__(256) void k_gemm2(
    const float* __restrict__ A, const float* __restrict__ W, float* __restrict__ Z, int N) {
  __shared__ float As[64][129];
  __shared__ float Bs[128 * 64];
  const int tid = threadIdx.x;
  const int row0 = blockIdx.x * 64;
  const int tx = tid & 15, ty = tid >> 4;
  float acc[4][4] = {};

  for (int k0 = 0; k0 < N_H; k0 += 128) {
#pragma unroll
    for (int i = 0; i < 8; i++) {
      int slot = tid + i * 256;
      int r = slot >> 5, c4 = slot & 31;
      float4 v = make_float4(0.f, 0.f, 0.f, 0.f);
      if (row0 + r < N)
        v = reinterpret_cast<const float4*>(A + (size_t)(row0 + r) * N_H + k0)[c4];
      As[r][c4 * 4 + 0] = v.x; As[r][c4 * 4 + 1] = v.y;
      As[r][c4 * 4 + 2] = v.z; As[r][c4 * 4 + 3] = v.w;
    }
#pragma unroll
    for (int i = 0; i < 8; i++) {
      int slot = tid + i * 256;   // W2 chunk is contiguous 128x64
      reinterpret_cast<float4*>(Bs)[slot] =
          reinterpret_cast<const float4*>(W + (size_t)k0 * N_OUT)[slot];
    }
    __syncthreads();
#pragma unroll 2
    for (int k = 0; k < 128; k++) {
      float a[4];
#pragma unroll
      for (int i = 0; i < 4; i++) a[i] = As[ty * 4 + i][k];
      float4 bv = *reinterpret_cast<const float4*>(Bs + k * 64 + tx * 4);
      float bb[4] = {bv.x, bv.y, bv.z, bv.w};
#pragma unroll
      for (int i = 0; i < 4; i++)
#pragma unroll
        for (int j = 0; j < 4; j++) acc[i][j] = fmaf(a[i], bb[j], acc[i][j]);
    }
    __syncthreads();
  }

#pragma unroll
  for (int i = 0; i < 4; i++) {
    int r = row0 + ty * 4 + i;
    if (r >= N) break;
    *reinterpret_cast<float4*>(Z + (size_t)r * N_OUT + tx * 4) =
        make_float4(acc[i][0], acc[i][1], acc[i][2], acc[i][3]);
  }
}

// ---------------- layer-2 scatter: out[dst] += z[src] ----------------
__global__ void k_scatter2(const float* __restrict__ z, const int* __restrict__ eidx,
                           float* __restrict__ out, int E, const int* __restrict__ flag) {
  long long t = (long long)blockIdx.x * 256 + threadIdx.x;
  int e = (int)(t >> 4);
  if (e >= E) return;
  int lane = (int)(t & 15);
  int stride = *flag;
  int s = eidx[(size_t)e * stride];
  int d = eidx[(size_t)(E + e) * stride];
  float4 v = reinterpret_cast<const float4*>(z + (size_t)s * N_OUT)[lane];
  float* o = out + (size_t)d * N_OUT + lane * 4;
  atomicAdd(o + 0, v.x);
  atomicAdd(o + 1, v.y);
  atomicAdd(o + 2, v.z);
  atomicAdd(o + 3, v.w);
}

// ---------------- final epilogue: out = out*norm + b2 ----------------
__global__ void k_out_epi(float* __restrict__ out, const float* __restrict__ norm,
                          const float* __restrict__ b2, int N) {
  int i = blockIdx.x * 256 + threadIdx.x;
  if (i < N * N_OUT) {
    int r = i >> 6, c = i & 63;
    out[i] = out[i] * norm[r] + b2[c];
  }
}

extern "C" void kernel_launch(void* const* d_in, const int* in_sizes, int n_in,
                              void* d_out, int out_size, void* d_ws, size_t ws_size,
                              hipStream_t stream) {
  const float* h  = (const float*)d_in[0];
  const float* W1 = (const float*)d_in[1];
  const float* b1 = (const float*)d_in[2];
  const float* W2 = (const float*)d_in[3];
  const float* b2 = (const float*)d_in[4];
  const int* eidx = (const int*)d_in[5];
  const int N = in_sizes[0] / N_IN;
  const int E = in_sizes[5] / 2;

  char* ws = (char*)d_ws;
  size_t off = 0;
  auto alloc = [&](size_t bytes) { void* p = ws + off; off += (bytes + 511) & ~(size_t)511; return p; };
  int*   eflag = (int*)alloc(sizeof(int));
  float* deg   = (float*)alloc((size_t)N * 4);
  float* norm  = (float*)alloc((size_t)N * 4);
  float* agg1  = (float*)alloc((size_t)N * N_IN * 4);
  float* h1s   = (float*)alloc((size_t)N * N_H * 4);
  float* z     = (float*)alloc((size_t)N * N_OUT * 4);
  float* out   = (float*)d_out;

  hipMemsetAsync(deg, 0, (size_t)N * 4, stream);
  hipMemsetAsync(agg1, 0, (size_t)N * N_IN * 4, stream);
  hipMemsetAsync(out, 0, (size_t)N * N_OUT * 4, stream);

  k_detect<<<1, 256, 0, stream>>>(eidx, E, eflag);
  k_deg<<<(E + 255) / 256, 256, 0, stream>>>(eidx, deg, E, eflag);
  k_norm<<<(N + 255) / 256, 256, 0, stream>>>(deg, norm, N);

  {
    long long threads = (long long)E * 32;
    k_scatter1<<<(int)((threads + 255) / 256), 256, 0, stream>>>(h, norm, eidx, agg1, E, eflag);
  }

  dim3 g1(4, (N + 63) / 64);
  k_gemm1<<<g1, 256, 0, stream>>>(agg1, W1, b1, norm, h1s, N);
  k_gemm2<<<(N + 63) / 64, 256, 0, stream>>>(h1s, W2, z, N);

  {
    long long threads = (long long)E * 16;
    k_scatter2<<<(int)((threads + 255) / 256), 256, 0, stream>>>(z, eidx, out, E, eflag);
  }
  k_out_epi<<<(int)(((long long)N * N_OUT + 255) / 256), 256, 0, stream>>>(out, norm, b2, N);
}

// Round 2
// 521.033 us; speedup vs baseline: 4.2939x; 4.2939x over previous
//
#include <hip/hip_runtime.h>
#include <stdint.h>

#define N_IN  128
#define N_H   256
#define N_OUT 64

// ---------------- Threefry-2x32 (JAX-compatible) ----------------
__device__ __forceinline__ void tf4(uint32_t& x0, uint32_t& x1,
                                    const int r0, const int r1, const int r2, const int r3) {
  x0 += x1; x1 = (x1 << r0) | (x1 >> (32 - r0)); x1 ^= x0;
  x0 += x1; x1 = (x1 << r1) | (x1 >> (32 - r1)); x1 ^= x0;
  x0 += x1; x1 = (x1 << r2) | (x1 >> (32 - r2)); x1 ^= x0;
  x0 += x1; x1 = (x1 << r3) | (x1 >> (32 - r3)); x1 ^= x0;
}

__device__ __forceinline__ uint2 threefry2x32(uint32_t k0, uint32_t k1, uint32_t x0, uint32_t x1) {
  const uint32_t k2 = k0 ^ k1 ^ 0x1BD11BDAu;
  x0 += k0; x1 += k1;
  tf4(x0, x1, 13, 15, 26, 6);   x0 += k1; x1 += k2 + 1u;
  tf4(x0, x1, 17, 29, 16, 24);  x0 += k2; x1 += k0 + 2u;
  tf4(x0, x1, 13, 15, 26, 6);   x0 += k0; x1 += k1 + 3u;
  tf4(x0, x1, 17, 29, 16, 24);  x0 += k1; x1 += k2 + 4u;
  tf4(x0, x1, 13, 15, 26, 6);   x0 += k2; x1 += k0 + 5u;
  return make_uint2(x0, x1);
}

__device__ __forceinline__ bool drop_keep(uint32_t idx) {
  // partitionable path: bits = o.x ^ o.y of threefry(key=(0,42), ctr=(0, idx))
  uint2 o = threefry2x32(0u, 42u, 0u, idx);
  uint32_t bits = o.x ^ o.y;
  return (bits & 0x80000000u) == 0u;   // keep <=> uniform < 0.5
}

// ---------------- edge-index layout detection (int64 vs int32) ----------------
__global__ void k_detect(const int* __restrict__ e, int E, int* __restrict__ flag) {
  __shared__ int s_nz;
  if (threadIdx.x == 0) s_nz = 0;
  __syncthreads();
  int n = E < 2048 ? E : 2048;
  for (int i = threadIdx.x; i < n; i += 256)
    if (e[2 * i + 1] != 0) atomicAdd(&s_nz, 1);
  __syncthreads();
  if (threadIdx.x == 0) *flag = (s_nz == 0) ? 2 : 1;
}

// ---------------- CSR build ----------------
__global__ void k_deg(const int* __restrict__ eidx, int* __restrict__ deg, int E,
                      const int* __restrict__ flag) {
  int e = blockIdx.x * 256 + threadIdx.x;
  if (e >= E) return;
  int stride = *flag;
  int d = eidx[(size_t)(E + e) * stride];
  atomicAdd(deg + d, 1);
}

// single-block exclusive scan: rowptr[0..N], rowptr[N] = E
__global__ __launch_bounds__(1024) void k_scan(const int* __restrict__ deg,
                                               int* __restrict__ rowptr, int N) {
  __shared__ int sums[1024];
  const int t = threadIdx.x;
  const int chunk = (N + 1023) >> 10;
  const int lo = t * chunk;
  const int hi = min(lo + chunk, N);
  int s = 0;
  for (int i = lo; i < hi; i++) s += deg[i];
  sums[t] = s;
  __syncthreads();
  for (int off = 1; off < 1024; off <<= 1) {
    int v = (t >= off) ? sums[t - off] : 0;
    __syncthreads();
    sums[t] += v;
    __syncthreads();
  }
  int run = (t == 0) ? 0 : sums[t - 1];
  for (int i = lo; i < hi; i++) { rowptr[i] = run; run += deg[i]; }
  if (t == 1023) rowptr[N] = sums[1023];
}

// norm = deg^-1/2 (clamped); cursor = rowptr copy for the fill
__global__ void k_normcur(const int* __restrict__ deg, const int* __restrict__ rowptr,
                          float* __restrict__ norm, int* __restrict__ cursor, int N) {
  int i = blockIdx.x * 256 + threadIdx.x;
  if (i < N) {
    int d = deg[i];
    norm[i] = d > 0 ? rsqrtf((float)d) : 1.0f;
    cursor[i] = rowptr[i];
  }
}

__global__ void k_fill(const int* __restrict__ eidx, int* __restrict__ cursor,
                       int* __restrict__ esrc, int E, const int* __restrict__ flag) {
  int e = blockIdx.x * 256 + threadIdx.x;
  if (e >= E) return;
  int stride = *flag;
  int s = eidx[(size_t)e * stride];
  int d = eidx[(size_t)(E + e) * stride];
  int pos = atomicAdd(cursor + d, 1);
  esrc[pos] = s;
}

// per-row insertion sort -> canonical (deterministic) accumulation order
__global__ void k_sort(int* __restrict__ esrc, const int* __restrict__ rowptr, int N) {
  int n = blockIdx.x * 256 + threadIdx.x;
  if (n >= N) return;
  int lo = rowptr[n], hi = rowptr[n + 1];
  for (int i = lo + 1; i < hi; i++) {
    int v = esrc[i];
    int j = i - 1;
    while (j >= lo && esrc[j] > v) { esrc[j + 1] = esrc[j]; j--; }
    esrc[j + 1] = v;
  }
}

// ---------------- layer-1 pull: agg[n] = sum_{s in row(n)} h[s]*norm[s] ----------------
// one wave per node; lane owns 2 consecutive floats (64*2 = 128 feats)
__global__ __launch_bounds__(256) void k_pull1(
    const float* __restrict__ h, const float* __restrict__ norm,
    const int* __restrict__ rowptr, const int* __restrict__ esrc,
    float* __restrict__ agg, int N) {
  int node = blockIdx.x * 4 + (threadIdx.x >> 6);
  if (node >= N) return;
  int lane = threadIdx.x & 63;
  int lo = rowptr[node], hi = rowptr[node + 1];
  float2 a0 = make_float2(0.f, 0.f), a1 = make_float2(0.f, 0.f);
  int e = lo;
  for (; e + 1 < hi; e += 2) {
    int s0 = esrc[e], s1 = esrc[e + 1];
    float n0 = norm[s0], n1 = norm[s1];
    float2 v0 = *reinterpret_cast<const float2*>(h + (size_t)s0 * N_IN + lane * 2);
    float2 v1 = *reinterpret_cast<const float2*>(h + (size_t)s1 * N_IN + lane * 2);
    a0.x = fmaf(v0.x, n0, a0.x); a0.y = fmaf(v0.y, n0, a0.y);
    a1.x = fmaf(v1.x, n1, a1.x); a1.y = fmaf(v1.y, n1, a1.y);
  }
  if (e < hi) {
    int s0 = esrc[e];
    float n0 = norm[s0];
    float2 v0 = *reinterpret_cast<const float2*>(h + (size_t)s0 * N_IN + lane * 2);
    a0.x = fmaf(v0.x, n0, a0.x); a0.y = fmaf(v0.y, n0, a0.y);
  }
  *reinterpret_cast<float2*>(agg + (size_t)node * N_IN + lane * 2) =
      make_float2(a0.x + a1.x, a0.y + a1.y);
}

// ---------------- GEMM1 fused: h1s = dropout(relu((agg1@W1)*norm + b1)) * norm ----------------
__global__ __launch_bounds__(256) void k_gemm1(
    const float* __restrict__ A, const float* __restrict__ W, const float* __restrict__ b,
    const float* __restrict__ norm, float* __restrict__ Hout, int N) {
  __shared__ float As[64][129];
  __shared__ float Bs[128 * 64];
  const int tid = threadIdx.x;
  const int bx = blockIdx.x;      // col tile: 0..3
  const int by = blockIdx.y;      // row tile
  const int row0 = by * 64;

#pragma unroll
  for (int i = 0; i < 8; i++) {
    int slot = tid + i * 256;
    int r = slot >> 5, c4 = slot & 31;
    float4 v = make_float4(0.f, 0.f, 0.f, 0.f);
    if (row0 + r < N) v = reinterpret_cast<const float4*>(A + (size_t)(row0 + r) * N_IN)[c4];
    As[r][c4 * 4 + 0] = v.x; As[r][c4 * 4 + 1] = v.y;
    As[r][c4 * 4 + 2] = v.z; As[r][c4 * 4 + 3] = v.w;
  }
#pragma unroll
  for (int i = 0; i < 8; i++) {
    int slot = tid + i * 256;
    int k = slot >> 4, c4 = slot & 15;
    reinterpret_cast<float4*>(Bs)[slot] =
        reinterpret_cast<const float4*>(W + (size_t)k * N_H + bx * 64)[c4];
  }
  __syncthreads();

  const int tx = tid & 15, ty = tid >> 4;
  float acc[4][4] = {};
#pragma unroll 2
  for (int k = 0; k < 128; k++) {
    float a[4];
#pragma unroll
    for (int i = 0; i < 4; i++) a[i] = As[ty * 4 + i][k];
    float4 bv = *reinterpret_cast<const float4*>(Bs + k * 64 + tx * 4);
    float bb[4] = {bv.x, bv.y, bv.z, bv.w};
#pragma unroll
    for (int i = 0; i < 4; i++)
#pragma unroll
      for (int j = 0; j < 4; j++) acc[i][j] = fmaf(a[i], bb[j], acc[i][j]);
  }

  const int c0 = bx * 64 + tx * 4;
#pragma unroll
  for (int i = 0; i < 4; i++) {
    int r = row0 + ty * 4 + i;
    if (r >= N) break;
    float nr = norm[r];
    float ov[4];
#pragma unroll
    for (int j = 0; j < 4; j++) {
      float v = acc[i][j] * nr + b[c0 + j];
      v = fmaxf(v, 0.f);
      uint32_t idx = (uint32_t)r * N_H + (uint32_t)(c0 + j);
      v = drop_keep(idx) ? v * 2.0f : 0.f;
      ov[j] = v * nr;   // pre-apply src norm for layer 2
    }
    *reinterpret_cast<float4*>(Hout + (size_t)r * N_H + c0) =
        make_float4(ov[0], ov[1], ov[2], ov[3]);
  }
}

// ---------------- GEMM2: z = h1s @ W2  ([N,256] @ [256,64]) ----------------
__global__ __launch_bounds__(256) void k_gemm2(
    const float* __restrict__ A, const float* __restrict__ W, float* __restrict__ Z, int N) {
  __shared__ float As[64][129];
  __shared__ float Bs[128 * 64];
  const int tid = threadIdx.x;
  const int row0 = blockIdx.x * 64;
  const int tx = tid & 15, ty = tid >> 4;
  float acc[4][4] = {};

  for (int k0 = 0; k0 < N_H; k0 += 128) {
#pragma unroll
    for (int i = 0; i < 8; i++) {
      int slot = tid + i * 256;
      int r = slot >> 5, c4 = slot & 31;
      float4 v = make_float4(0.f, 0.f, 0.f, 0.f);
      if (row0 + r < N)
        v = reinterpret_cast<const float4*>(A + (size_t)(row0 + r) * N_H + k0)[c4];
      As[r][c4 * 4 + 0] = v.x; As[r][c4 * 4 + 1] = v.y;
      As[r][c4 * 4 + 2] = v.z; As[r][c4 * 4 + 3] = v.w;
    }
#pragma unroll
    for (int i = 0; i < 8; i++) {
      int slot = tid + i * 256;
      reinterpret_cast<float4*>(Bs)[slot] =
          reinterpret_cast<const float4*>(W + (size_t)k0 * N_OUT)[slot];
    }
    __syncthreads();
#pragma unroll 2
    for (int k = 0; k < 128; k++) {
      float a[4];
#pragma unroll
      for (int i = 0; i < 4; i++) a[i] = As[ty * 4 + i][k];
      float4 bv = *reinterpret_cast<const float4*>(Bs + k * 64 + tx * 4);
      float bb[4] = {bv.x, bv.y, bv.z, bv.w};
#pragma unroll
      for (int i = 0; i < 4; i++)
#pragma unroll
        for (int j = 0; j < 4; j++) acc[i][j] = fmaf(a[i], bb[j], acc[i][j]);
    }
    __syncthreads();
  }

#pragma unroll
  for (int i = 0; i < 4; i++) {
    int r = row0 + ty * 4 + i;
    if (r >= N) break;
    *reinterpret_cast<float4*>(Z + (size_t)r * N_OUT + tx * 4) =
        make_float4(acc[i][0], acc[i][1], acc[i][2], acc[i][3]);
  }
}

// ---------------- layer-2 pull fused epilogue: out[n] = (sum z[s]) * norm[n] + b2 ----------------
// one wave per node; lane owns feature `lane` (64 feats)
__global__ __launch_bounds__(256) void k_pull2(
    const float* __restrict__ z, const float* __restrict__ norm,
    const float* __restrict__ b2, const int* __restrict__ rowptr,
    const int* __restrict__ esrc, float* __restrict__ out, int N) {
  int node = blockIdx.x * 4 + (threadIdx.x >> 6);
  if (node >= N) return;
  int lane = threadIdx.x & 63;
  int lo = rowptr[node], hi = rowptr[node + 1];
  float a0 = 0.f, a1 = 0.f;
  int e = lo;
  for (; e + 1 < hi; e += 2) {
    int s0 = esrc[e], s1 = esrc[e + 1];
    a0 += z[(size_t)s0 * N_OUT + lane];
    a1 += z[(size_t)s1 * N_OUT + lane];
  }
  if (e < hi) a0 += z[(size_t)esrc[e] * N_OUT + lane];
  out[(size_t)node * N_OUT + lane] = (a0 + a1) * norm[node] + b2[lane];
}

extern "C" void kernel_launch(void* const* d_in, const int* in_sizes, int n_in,
                              void* d_out, int out_size, void* d_ws, size_t ws_size,
                              hipStream_t stream) {
  const float* h  = (const float*)d_in[0];
  const float* W1 = (const float*)d_in[1];
  const float* b1 = (const float*)d_in[2];
  const float* W2 = (const float*)d_in[3];
  const float* b2 = (const float*)d_in[4];
  const int* eidx = (const int*)d_in[5];
  const int N = in_sizes[0] / N_IN;
  const int E = in_sizes[5] / 2;

  char* ws = (char*)d_ws;
  size_t off = 0;
  auto alloc = [&](size_t bytes) { void* p = ws + off; off += (bytes + 511) & ~(size_t)511; return p; };
  int*   eflag  = (int*)alloc(sizeof(int));
  int*   deg    = (int*)alloc((size_t)N * 4);
  int*   rowptr = (int*)alloc((size_t)(N + 1) * 4);
  int*   cursor = (int*)alloc((size_t)N * 4);
  float* norm   = (float*)alloc((size_t)N * 4);
  int*   esrc   = (int*)alloc((size_t)E * 4);
  float* agg1   = (float*)alloc((size_t)N * N_IN * 4);
  float* h1s    = (float*)alloc((size_t)N * N_H * 4);
  float* z      = agg1;               // agg1 is dead after gemm1; reuse for z
  float* out    = (float*)d_out;

  hipMemsetAsync(deg, 0, (size_t)N * 4, stream);

  k_detect<<<1, 256, 0, stream>>>(eidx, E, eflag);
  k_deg<<<(E + 255) / 256, 256, 0, stream>>>(eidx, deg, E, eflag);
  k_scan<<<1, 1024, 0, stream>>>(deg, rowptr, N);
  k_normcur<<<(N + 255) / 256, 256, 0, stream>>>(deg, rowptr, norm, cursor, N);
  k_fill<<<(E + 255) / 256, 256, 0, stream>>>(eidx, cursor, esrc, E, eflag);
  k_sort<<<(N + 255) / 256, 256, 0, stream>>>(esrc, rowptr, N);

  k_pull1<<<(N + 3) / 4, 256, 0, stream>>>(h, norm, rowptr, esrc, agg1, N);

  dim3 g1(4, (N + 63) / 64);
  k_gemm1<<<g1, 256, 0, stream>>>(agg1, W1, b1, norm, h1s, N);
  k_gemm2<<<(N + 63) / 64, 256, 0, stream>>>(h1s, W2, z, N);

  k_pull2<<<(N + 3) / 4, 256, 0, stream>>>(z, norm, b2, rowptr, esrc, out, N);
}

// Round 3
// 386.552 us; speedup vs baseline: 5.7878x; 1.3479x over previous
//
#include <hip/hip_runtime.h>
#include <stdint.h>

#define N_IN  128
#define N_H   256
#define N_OUT 64

typedef __attribute__((ext_vector_type(8))) __bf16 bf16x8;
typedef __attribute__((ext_vector_type(4))) float f32x4;

// ---------------- Threefry-2x32 (JAX-compatible) ----------------
__device__ __forceinline__ void tf4(uint32_t& x0, uint32_t& x1,
                                    const int r0, const int r1, const int r2, const int r3) {
  x0 += x1; x1 = (x1 << r0) | (x1 >> (32 - r0)); x1 ^= x0;
  x0 += x1; x1 = (x1 << r1) | (x1 >> (32 - r1)); x1 ^= x0;
  x0 += x1; x1 = (x1 << r2) | (x1 >> (32 - r2)); x1 ^= x0;
  x0 += x1; x1 = (x1 << r3) | (x1 >> (32 - r3)); x1 ^= x0;
}

__device__ __forceinline__ uint2 threefry2x32(uint32_t k0, uint32_t k1, uint32_t x0, uint32_t x1) {
  const uint32_t k2 = k0 ^ k1 ^ 0x1BD11BDAu;
  x0 += k0; x1 += k1;
  tf4(x0, x1, 13, 15, 26, 6);   x0 += k1; x1 += k2 + 1u;
  tf4(x0, x1, 17, 29, 16, 24);  x0 += k2; x1 += k0 + 2u;
  tf4(x0, x1, 13, 15, 26, 6);   x0 += k0; x1 += k1 + 3u;
  tf4(x0, x1, 17, 29, 16, 24);  x0 += k1; x1 += k2 + 4u;
  tf4(x0, x1, 13, 15, 26, 6);   x0 += k2; x1 += k0 + 5u;
  return make_uint2(x0, x1);
}

__device__ __forceinline__ bool drop_keep(uint32_t idx) {
  uint2 o = threefry2x32(0u, 42u, 0u, idx);
  uint32_t bits = o.x ^ o.y;
  return (bits & 0x80000000u) == 0u;   // keep <=> uniform < 0.5
}

// split f32 -> (hi,lo) bf16 bit patterns packed in one u32: (hi<<16)|lo
__device__ __forceinline__ uint32_t pack_hilo(float v) {
  uint32_t bits = __builtin_bit_cast(uint32_t, v);
  uint32_t hi = bits & 0xffff0000u;
  float lo = v - __builtin_bit_cast(float, hi);
  uint32_t lob = __builtin_bit_cast(uint32_t, lo) >> 16;
  return hi | lob;
}

// ---------------- edge-index layout detection (int64 vs int32) ----------------
__global__ void k_detect(const int* __restrict__ e, int E, int* __restrict__ flag) {
  __shared__ int s_nz;
  if (threadIdx.x == 0) s_nz = 0;
  __syncthreads();
  int n = E < 2048 ? E : 2048;
  for (int i = threadIdx.x; i < n; i += 256)
    if (e[2 * i + 1] != 0) atomicAdd(&s_nz, 1);
  __syncthreads();
  if (threadIdx.x == 0) *flag = (s_nz == 0) ? 2 : 1;
}

// ---------------- CSR build ----------------
__global__ void k_deg(const int* __restrict__ eidx, int* __restrict__ deg, int E,
                      const int* __restrict__ flag) {
  int e = blockIdx.x * 256 + threadIdx.x;
  if (e >= E) return;
  int stride = *flag;
  int d = eidx[(size_t)(E + e) * stride];
  atomicAdd(deg + d, 1);
}

__global__ __launch_bounds__(1024) void k_scan(const int* __restrict__ deg,
                                               int* __restrict__ rowptr, int N) {
  __shared__ int sums[1024];
  const int t = threadIdx.x;
  const int chunk = (N + 1023) >> 10;
  const int lo = t * chunk;
  const int hi = min(lo + chunk, N);
  int s = 0;
  for (int i = lo; i < hi; i++) s += deg[i];
  sums[t] = s;
  __syncthreads();
  for (int off = 1; off < 1024; off <<= 1) {
    int v = (t >= off) ? sums[t - off] : 0;
    __syncthreads();
    sums[t] += v;
    __syncthreads();
  }
  int run = (t == 0) ? 0 : sums[t - 1];
  for (int i = lo; i < hi; i++) { rowptr[i] = run; run += deg[i]; }
  if (t == 1023) rowptr[N] = sums[1023];
}

__global__ void k_normcur(const int* __restrict__ deg, const int* __restrict__ rowptr,
                          float* __restrict__ norm, int* __restrict__ cursor, int N) {
  int i = blockIdx.x * 256 + threadIdx.x;
  if (i < N) {
    int d = deg[i];
    norm[i] = d > 0 ? rsqrtf((float)d) : 1.0f;
    cursor[i] = rowptr[i];
  }
}

__global__ void k_fill(const int* __restrict__ eidx, int* __restrict__ cursor,
                       int* __restrict__ esrc, int E, const int* __restrict__ flag) {
  int e = blockIdx.x * 256 + threadIdx.x;
  if (e >= E) return;
  int stride = *flag;
  int s = eidx[(size_t)e * stride];
  int d = eidx[(size_t)(E + e) * stride];
  int pos = atomicAdd(cursor + d, 1);
  esrc[pos] = s;
}

// per-row insertion sort in LDS (canonical deterministic order)
__global__ __launch_bounds__(256) void k_sortlds(int* __restrict__ esrc,
                                                 const int* __restrict__ rowptr, int N) {
  __shared__ int buf[64 * 256];   // 64 KB: 64 slots per thread, column-major (stride 256)
  int n = blockIdx.x * 256 + threadIdx.x;
  if (n >= N) return;
  const int t = threadIdx.x;
  int lo = rowptr[n], hi = rowptr[n + 1], d = hi - lo;
  if (d <= 64) {
    for (int i = 0; i < d; i++) buf[i * 256 + t] = esrc[lo + i];
    for (int i = 1; i < d; i++) {
      int v = buf[i * 256 + t];
      int j = i - 1;
      while (j >= 0 && buf[j * 256 + t] > v) { buf[(j + 1) * 256 + t] = buf[j * 256 + t]; j--; }
      buf[(j + 1) * 256 + t] = v;
    }
    for (int i = 0; i < d; i++) esrc[lo + i] = buf[i * 256 + t];
  } else {
    for (int i = lo + 1; i < hi; i++) {
      int v = esrc[i];
      int j = i - 1;
      while (j >= lo && esrc[j] > v) { esrc[j + 1] = esrc[j]; j--; }
      esrc[j + 1] = v;
    }
  }
}

// ---------------- layer-1 pull: aggP[n] = pack(sum h[s]*norm[s]) ----------------
// one wave per node; lane owns 2 consecutive floats; 4-edge unroll for MLP
__global__ __launch_bounds__(256) void k_pull1(
    const float* __restrict__ h, const float* __restrict__ norm,
    const int* __restrict__ rowptr, const int* __restrict__ esrc,
    uint32_t* __restrict__ aggP, int N) {
  int node = blockIdx.x * 4 + (threadIdx.x >> 6);
  if (node >= N) return;
  int lane = threadIdx.x & 63;
  int lo = rowptr[node], hi = rowptr[node + 1];
  float2 a0 = {0.f, 0.f}, a1 = {0.f, 0.f}, a2 = {0.f, 0.f}, a3 = {0.f, 0.f};
  int e = lo;
  for (; e + 3 < hi; e += 4) {
    int s0 = esrc[e], s1 = esrc[e + 1], s2 = esrc[e + 2], s3 = esrc[e + 3];
    float n0 = norm[s0], n1 = norm[s1], n2 = norm[s2], n3 = norm[s3];
    float2 v0 = *reinterpret_cast<const float2*>(h + (size_t)s0 * N_IN + lane * 2);
    float2 v1 = *reinterpret_cast<const float2*>(h + (size_t)s1 * N_IN + lane * 2);
    float2 v2 = *reinterpret_cast<const float2*>(h + (size_t)s2 * N_IN + lane * 2);
    float2 v3 = *reinterpret_cast<const float2*>(h + (size_t)s3 * N_IN + lane * 2);
    a0.x = fmaf(v0.x, n0, a0.x); a0.y = fmaf(v0.y, n0, a0.y);
    a1.x = fmaf(v1.x, n1, a1.x); a1.y = fmaf(v1.y, n1, a1.y);
    a2.x = fmaf(v2.x, n2, a2.x); a2.y = fmaf(v2.y, n2, a2.y);
    a3.x = fmaf(v3.x, n3, a3.x); a3.y = fmaf(v3.y, n3, a3.y);
  }
  for (; e < hi; e++) {
    int s0 = esrc[e];
    float n0 = norm[s0];
    float2 v0 = *reinterpret_cast<const float2*>(h + (size_t)s0 * N_IN + lane * 2);
    a0.x = fmaf(v0.x, n0, a0.x); a0.y = fmaf(v0.y, n0, a0.y);
  }
  float rx = (a0.x + a1.x) + (a2.x + a3.x);
  float ry = (a0.y + a1.y) + (a2.y + a3.y);
  uint2 p = make_uint2(pack_hilo(rx), pack_hilo(ry));
  *reinterpret_cast<uint2*>(aggP + (size_t)node * N_IN + lane * 2) = p;
}

// ---------------- W pack: fragment-order (hi,lo) bf16 planes ----------------
// slot g = (ct*nks + ks)*64 + lane; element j: B[k = ks*32+(lane>>4)*8+j][col = ct*16+(lane&15)]
__global__ void k_packW(const float* __restrict__ W, uint4* __restrict__ WH,
                        uint4* __restrict__ WL, int Ncols, int nct, int nks) {
  int g = blockIdx.x * 256 + threadIdx.x;
  if (g >= nct * nks * 64) return;
  int lane = g & 63;
  int grp = g >> 6;
  int ks = grp % nks, ct = grp / nks;
  int k0 = ks * 32 + (lane >> 4) * 8;
  int col = ct * 16 + (lane & 15);
  uint32_t hb[8], lb[8];
#pragma unroll
  for (int j = 0; j < 8; j++) {
    float w = W[(size_t)(k0 + j) * Ncols + col];
    uint32_t bits = __builtin_bit_cast(uint32_t, w);
    uint32_t hi = bits & 0xffff0000u;
    float lo = w - __builtin_bit_cast(float, hi);
    hb[j] = hi >> 16;
    lb[j] = __builtin_bit_cast(uint32_t, lo) >> 16;
  }
  WH[g] = make_uint4(hb[0] | (hb[1] << 16), hb[2] | (hb[3] << 16),
                     hb[4] | (hb[5] << 16), hb[6] | (hb[7] << 16));
  WL[g] = make_uint4(lb[0] | (lb[1] << 16), lb[2] | (lb[3] << 16),
                     lb[4] | (lb[5] << 16), lb[6] | (lb[7] << 16));
}

// ---------------- GEMM1 (split-bf16 MFMA, no LDS) ----------------
// block = 4 waves; wave w: rows [blk*64 + w*16, +16), all 256 cols (16 col-tiles)
__global__ __launch_bounds__(256) void k_gemm1_mfma(
    const uint32_t* __restrict__ aggP, const uint4* __restrict__ WH,
    const uint4* __restrict__ WL, const float* __restrict__ b1,
    const float* __restrict__ norm, uint32_t* __restrict__ h1sP, int Nn) {
  const int tid = threadIdx.x;
  const int wave = tid >> 6, lane = tid & 63;
  const int row0 = blockIdx.x * 64 + wave * 16;
  const int lrow = lane & 15, lk = lane >> 4;
  int arow = row0 + lrow; if (arow >= Nn) arow = Nn - 1;

  f32x4 acc[16];
#pragma unroll
  for (int ct = 0; ct < 16; ct++) acc[ct] = f32x4{0.f, 0.f, 0.f, 0.f};

#pragma unroll
  for (int ks = 0; ks < 4; ks++) {
    const uint4* ap = reinterpret_cast<const uint4*>(aggP + (size_t)arow * N_IN + ks * 32 + lk * 8);
    uint4 p0 = ap[0], p1 = ap[1];
    uint32_t pw[8] = {p0.x, p0.y, p0.z, p0.w, p1.x, p1.y, p1.z, p1.w};
    union { ushort u[8]; bf16x8 v; } ah, al;
#pragma unroll
    for (int j = 0; j < 8; j++) { ah.u[j] = (ushort)(pw[j] >> 16); al.u[j] = (ushort)(pw[j] & 0xffffu); }
#pragma unroll
    for (int ct = 0; ct < 16; ct++) {
      union { uint4 q; bf16x8 v; } bh, bl;
      bh.q = WH[(ct * 4 + ks) * 64 + lane];
      bl.q = WL[(ct * 4 + ks) * 64 + lane];
      acc[ct] = __builtin_amdgcn_mfma_f32_16x16x32_bf16(ah.v, bh.v, acc[ct], 0, 0, 0);
      acc[ct] = __builtin_amdgcn_mfma_f32_16x16x32_bf16(ah.v, bl.v, acc[ct], 0, 0, 0);
      acc[ct] = __builtin_amdgcn_mfma_f32_16x16x32_bf16(al.v, bh.v, acc[ct], 0, 0, 0);
    }
  }

  // epilogue: *norm[row] + b1 -> relu -> dropout -> *norm[row] -> pack hi/lo
  const int colb = lane & 15, rgrp = lane >> 4;
#pragma unroll
  for (int r = 0; r < 4; r++) {
    int row = row0 + rgrp * 4 + r;
    if (row >= Nn) continue;
    float nr = norm[row];
#pragma unroll
    for (int ct = 0; ct < 16; ct++) {
      int col = ct * 16 + colb;
      float v = fmaf(acc[ct][r], nr, b1[col]);
      v = fmaxf(v, 0.f);
      v = drop_keep((uint32_t)row * (uint32_t)N_H + (uint32_t)col) ? v * 2.0f : 0.f;
      v *= nr;   // pre-apply src norm for layer 2
      h1sP[(size_t)row * N_H + col] = pack_hilo(v);
    }
  }
}

// ---------------- GEMM2 (split-bf16 MFMA): z = h1s @ W2 ----------------
__global__ __launch_bounds__(256) void k_gemm2_mfma(
    const uint32_t* __restrict__ h1sP, const uint4* __restrict__ WH,
    const uint4* __restrict__ WL, float* __restrict__ z, int Nn) {
  const int tid = threadIdx.x;
  const int wave = tid >> 6, lane = tid & 63;
  const int row0 = blockIdx.x * 64 + wave * 16;
  const int lrow = lane & 15, lk = lane >> 4;
  int arow = row0 + lrow; if (arow >= Nn) arow = Nn - 1;

  f32x4 acc[4];
#pragma unroll
  for (int ct = 0; ct < 4; ct++) acc[ct] = f32x4{0.f, 0.f, 0.f, 0.f};

#pragma unroll
  for (int ks = 0; ks < 8; ks++) {
    const uint4* ap = reinterpret_cast<const uint4*>(h1sP + (size_t)arow * N_H + ks * 32 + lk * 8);
    uint4 p0 = ap[0], p1 = ap[1];
    uint32_t pw[8] = {p0.x, p0.y, p0.z, p0.w, p1.x, p1.y, p1.z, p1.w};
    union { ushort u[8]; bf16x8 v; } ah, al;
#pragma unroll
    for (int j = 0; j < 8; j++) { ah.u[j] = (ushort)(pw[j] >> 16); al.u[j] = (ushort)(pw[j] & 0xffffu); }
#pragma unroll
    for (int ct = 0; ct < 4; ct++) {
      union { uint4 q; bf16x8 v; } bh, bl;
      bh.q = WH[(ct * 8 + ks) * 64 + lane];
      bl.q = WL[(ct * 8 + ks) * 64 + lane];
      acc[ct] = __builtin_amdgcn_mfma_f32_16x16x32_bf16(ah.v, bh.v, acc[ct], 0, 0, 0);
      acc[ct] = __builtin_amdgcn_mfma_f32_16x16x32_bf16(ah.v, bl.v, acc[ct], 0, 0, 0);
      acc[ct] = __builtin_amdgcn_mfma_f32_16x16x32_bf16(al.v, bh.v, acc[ct], 0, 0, 0);
    }
  }

  const int colb = lane & 15, rgrp = lane >> 4;
#pragma unroll
  for (int r = 0; r < 4; r++) {
    int row = row0 + rgrp * 4 + r;
    if (row >= Nn) continue;
#pragma unroll
    for (int ct = 0; ct < 4; ct++)
      z[(size_t)row * N_OUT + ct * 16 + colb] = acc[ct][r];
  }
}

// ---------------- layer-2 pull fused epilogue ----------------
__global__ __launch_bounds__(256) void k_pull2(
    const float* __restrict__ z, const float* __restrict__ norm,
    const float* __restrict__ b2, const int* __restrict__ rowptr,
    const int* __restrict__ esrc, float* __restrict__ out, int N) {
  int node = blockIdx.x * 4 + (threadIdx.x >> 6);
  if (node >= N) return;
  int lane = threadIdx.x & 63;
  int lo = rowptr[node], hi = rowptr[node + 1];
  float a0 = 0.f, a1 = 0.f, a2 = 0.f, a3 = 0.f;
  int e = lo;
  for (; e + 3 < hi; e += 4) {
    int s0 = esrc[e], s1 = esrc[e + 1], s2 = esrc[e + 2], s3 = esrc[e + 3];
    a0 += z[(size_t)s0 * N_OUT + lane];
    a1 += z[(size_t)s1 * N_OUT + lane];
    a2 += z[(size_t)s2 * N_OUT + lane];
    a3 += z[(size_t)s3 * N_OUT + lane];
  }
  for (; e < hi; e++) a0 += z[(size_t)esrc[e] * N_OUT + lane];
  out[(size_t)node * N_OUT + lane] = ((a0 + a1) + (a2 + a3)) * norm[node] + b2[lane];
}

extern "C" void kernel_launch(void* const* d_in, const int* in_sizes, int n_in,
                              void* d_out, int out_size, void* d_ws, size_t ws_size,
                              hipStream_t stream) {
  const float* h  = (const float*)d_in[0];
  const float* W1 = (const float*)d_in[1];
  const float* b1 = (const float*)d_in[2];
  const float* W2 = (const float*)d_in[3];
  const float* b2 = (const float*)d_in[4];
  const int* eidx = (const int*)d_in[5];
  const int N = in_sizes[0] / N_IN;
  const int E = in_sizes[5] / 2;

  char* ws = (char*)d_ws;
  size_t off = 0;
  auto alloc = [&](size_t bytes) { void* p = ws + off; off += (bytes + 511) & ~(size_t)511; return p; };
  int*      eflag  = (int*)alloc(sizeof(int));
  int*      deg    = (int*)alloc((size_t)N * 4);
  int*      rowptr = (int*)alloc((size_t)(N + 1) * 4);
  int*      cursor = (int*)alloc((size_t)N * 4);
  float*    norm   = (float*)alloc((size_t)N * 4);
  int*      esrc   = (int*)alloc((size_t)E * 4);
  uint4*    W1H    = (uint4*)alloc((size_t)16 * 4 * 64 * 16);
  uint4*    W1L    = (uint4*)alloc((size_t)16 * 4 * 64 * 16);
  uint4*    W2H    = (uint4*)alloc((size_t)4 * 8 * 64 * 16);
  uint4*    W2L    = (uint4*)alloc((size_t)4 * 8 * 64 * 16);
  uint32_t* aggP   = (uint32_t*)alloc((size_t)N * N_IN * 4);
  uint32_t* h1sP   = (uint32_t*)alloc((size_t)N * N_H * 4);
  float*    z      = (float*)aggP;   // aggP dead after gemm1; z is 12.8 MB < 25.6 MB
  float*    out    = (float*)d_out;

  hipMemsetAsync(deg, 0, (size_t)N * 4, stream);

  // W packing is graph-independent: launch first
  k_packW<<<(16 * 4 * 64 + 255) / 256, 256, 0, stream>>>(W1, W1H, W1L, N_H, 16, 4);
  k_packW<<<(4 * 8 * 64 + 255) / 256, 256, 0, stream>>>(W2, W2H, W2L, N_OUT, 4, 8);

  k_detect<<<1, 256, 0, stream>>>(eidx, E, eflag);
  k_deg<<<(E + 255) / 256, 256, 0, stream>>>(eidx, deg, E, eflag);
  k_scan<<<1, 1024, 0, stream>>>(deg, rowptr, N);
  k_normcur<<<(N + 255) / 256, 256, 0, stream>>>(deg, rowptr, norm, cursor, N);
  k_fill<<<(E + 255) / 256, 256, 0, stream>>>(eidx, cursor, esrc, E, eflag);
  k_sortlds<<<(N + 255) / 256, 256, 0, stream>>>(esrc, rowptr, N);

  k_pull1<<<(N + 3) / 4, 256, 0, stream>>>(h, norm, rowptr, esrc, aggP, N);

  k_gemm1_mfma<<<(N + 63) / 64, 256, 0, stream>>>(aggP, W1H, W1L, b1, norm, h1sP, N);
  k_gemm2_mfma<<<(N + 63) / 64, 256, 0, stream>>>(h1sP, W2H, W2L, z, N);

  k_pull2<<<(N + 3) / 4, 256, 0, stream>>>(z, norm, b2, rowptr, esrc, out, N);
}

// Round 4
// 318.889 us; speedup vs baseline: 7.0159x; 1.2122x over previous
//
#include <hip/hip_runtime.h>
#include <stdint.h>

#define N_IN  128
#define N_H   256
#define N_OUT 64

typedef __attribute__((ext_vector_type(8))) __bf16 bf16x8;
typedef __attribute__((ext_vector_type(4))) float f32x4;

// ---------------- Threefry-2x32 (JAX-compatible) ----------------
__device__ __forceinline__ void tf4(uint32_t& x0, uint32_t& x1,
                                    const int r0, const int r1, const int r2, const int r3) {
  x0 += x1; x1 = (x1 << r0) | (x1 >> (32 - r0)); x1 ^= x0;
  x0 += x1; x1 = (x1 << r1) | (x1 >> (32 - r1)); x1 ^= x0;
  x0 += x1; x1 = (x1 << r2) | (x1 >> (32 - r2)); x1 ^= x0;
  x0 += x1; x1 = (x1 << r3) | (x1 >> (32 - r3)); x1 ^= x0;
}

__device__ __forceinline__ uint2 threefry2x32(uint32_t k0, uint32_t k1, uint32_t x0, uint32_t x1) {
  const uint32_t k2 = k0 ^ k1 ^ 0x1BD11BDAu;
  x0 += k0; x1 += k1;
  tf4(x0, x1, 13, 15, 26, 6);   x0 += k1; x1 += k2 + 1u;
  tf4(x0, x1, 17, 29, 16, 24);  x0 += k2; x1 += k0 + 2u;
  tf4(x0, x1, 13, 15, 26, 6);   x0 += k0; x1 += k1 + 3u;
  tf4(x0, x1, 17, 29, 16, 24);  x0 += k1; x1 += k2 + 4u;
  tf4(x0, x1, 13, 15, 26, 6);   x0 += k2; x1 += k0 + 5u;
  return make_uint2(x0, x1);
}

__device__ __forceinline__ bool drop_keep(uint32_t idx) {
  uint2 o = threefry2x32(0u, 42u, 0u, idx);
  uint32_t bits = o.x ^ o.y;
  return (bits & 0x80000000u) == 0u;   // keep <=> uniform < 0.5
}

// split f32 -> (hi,lo) bf16 bit patterns packed in one u32: (hi<<16)|lo
__device__ __forceinline__ uint32_t pack_hilo(float v) {
  uint32_t bits = __builtin_bit_cast(uint32_t, v);
  uint32_t hi = bits & 0xffff0000u;
  float lo = v - __builtin_bit_cast(float, hi);
  uint32_t lob = __builtin_bit_cast(uint32_t, lo) >> 16;
  return hi | lob;
}

// ---------------- edge-index layout detection (int64 vs int32) ----------------
__global__ void k_detect(const int* __restrict__ e, int E, int* __restrict__ flag) {
  __shared__ int s_nz;
  if (threadIdx.x == 0) s_nz = 0;
  __syncthreads();
  int n = E < 2048 ? E : 2048;
  for (int i = threadIdx.x; i < n; i += 256)
    if (e[2 * i + 1] != 0) atomicAdd(&s_nz, 1);
  __syncthreads();
  if (threadIdx.x == 0) *flag = (s_nz == 0) ? 2 : 1;
}

// ---------------- CSR build ----------------
__global__ void k_deg(const int* __restrict__ eidx, int* __restrict__ deg, int E,
                      const int* __restrict__ flag) {
  int e = blockIdx.x * 256 + threadIdx.x;
  if (e >= E) return;
  int stride = *flag;
  int d = eidx[(size_t)(E + e) * stride];
  atomicAdd(deg + d, 1);
}

// hierarchical scan, phase A: per-block (1024 elems) sum
__global__ __launch_bounds__(256) void k_scanA(const int* __restrict__ deg,
                                               int* __restrict__ bsum, int N) {
  const int b = blockIdx.x, t = threadIdx.x;
  const int base = b * 1024 + t * 4;
  int s = 0;
  if (base + 3 < N) {
    int4 v = *reinterpret_cast<const int4*>(deg + base);
    s = v.x + v.y + v.z + v.w;
  } else {
    for (int i = 0; i < 4; i++) if (base + i < N) s += deg[base + i];
  }
  __shared__ int ws[4];
#pragma unroll
  for (int off = 32; off; off >>= 1) s += __shfl_down(s, off);
  if ((t & 63) == 0) ws[t >> 6] = s;
  __syncthreads();
  if (t == 0) bsum[b] = ws[0] + ws[1] + ws[2] + ws[3];
}

// phase B: single-wave exclusive scan of block sums (NB <= 64); writes rowptr[N]
__global__ void k_scanB(const int* __restrict__ bsum, int* __restrict__ boff,
                        int* __restrict__ rowptrN, int NB) {
  int t = threadIdx.x;   // 64 threads
  int x = (t < NB) ? bsum[t] : 0;
  int v = x;
#pragma unroll
  for (int off = 1; off < 64; off <<= 1) {
    int u = __shfl_up(v, off);
    if (t >= off) v += u;
  }
  if (t < NB) boff[t] = v - x;
  if (t == 63) *rowptrN = v;
}

// phase C: per-block local scan + boff, fused norm + cursor
__global__ __launch_bounds__(256) void k_scanC(const int* __restrict__ deg,
                                               const int* __restrict__ boff,
                                               int* __restrict__ rowptr,
                                               float* __restrict__ norm,
                                               int* __restrict__ cursor, int N) {
  __shared__ int sums[256];
  const int b = blockIdx.x, t = threadIdx.x;
  const int base = b * 1024 + t * 4;
  int d[4]; int s = 0;
#pragma unroll
  for (int i = 0; i < 4; i++) { d[i] = (base + i < N) ? deg[base + i] : 0; s += d[i]; }
  sums[t] = s;
  __syncthreads();
  for (int off = 1; off < 256; off <<= 1) {
    int u = (t >= off) ? sums[t - off] : 0;
    __syncthreads();
    sums[t] += u;
    __syncthreads();
  }
  int run = boff[b] + ((t == 0) ? 0 : sums[t - 1]);
#pragma unroll
  for (int i = 0; i < 4; i++) {
    if (base + i < N) {
      rowptr[base + i] = run;
      cursor[base + i] = run;
      norm[base + i] = d[i] > 0 ? rsqrtf((float)d[i]) : 1.0f;
      run += d[i];
    }
  }
}

__global__ void k_fill(const int* __restrict__ eidx, int* __restrict__ cursor,
                       int* __restrict__ esrc, int E, const int* __restrict__ flag) {
  int e = blockIdx.x * 256 + threadIdx.x;
  if (e >= E) return;
  int stride = *flag;
  int s = eidx[(size_t)e * stride];
  int d = eidx[(size_t)(E + e) * stride];
  int pos = atomicAdd(cursor + d, 1);
  esrc[pos] = s;
}

// per-row insertion sort in LDS (canonical deterministic order)
__global__ __launch_bounds__(256) void k_sortlds(int* __restrict__ esrc,
                                                 const int* __restrict__ rowptr, int N) {
  __shared__ int buf[64 * 256];   // 64 KB: 64 slots per thread, column-major (stride 256)
  int n = blockIdx.x * 256 + threadIdx.x;
  if (n >= N) return;
  const int t = threadIdx.x;
  int lo = rowptr[n], hi = rowptr[n + 1], d = hi - lo;
  if (d <= 64) {
    for (int i = 0; i < d; i++) buf[i * 256 + t] = esrc[lo + i];
    for (int i = 1; i < d; i++) {
      int v = buf[i * 256 + t];
      int j = i - 1;
      while (j >= 0 && buf[j * 256 + t] > v) { buf[(j + 1) * 256 + t] = buf[j * 256 + t]; j--; }
      buf[(j + 1) * 256 + t] = v;
    }
    for (int i = 0; i < d; i++) esrc[lo + i] = buf[i * 256 + t];
  } else {
    for (int i = lo + 1; i < hi; i++) {
      int v = esrc[i];
      int j = i - 1;
      while (j >= lo && esrc[j] > v) { esrc[j + 1] = esrc[j]; j--; }
      esrc[j + 1] = v;
    }
  }
}

// ---------------- layer-1 pull: aggP[n] = pack(sum h[s]*norm[s]) ----------------
__global__ __launch_bounds__(256) void k_pull1(
    const float* __restrict__ h, const float* __restrict__ norm,
    const int* __restrict__ rowptr, const int* __restrict__ esrc,
    uint32_t* __restrict__ aggP, int N) {
  int node = blockIdx.x * 4 + (threadIdx.x >> 6);
  if (node >= N) return;
  int lane = threadIdx.x & 63;
  int lo = rowptr[node], hi = rowptr[node + 1];
  float2 a0 = {0.f, 0.f}, a1 = {0.f, 0.f}, a2 = {0.f, 0.f}, a3 = {0.f, 0.f};
  int e = lo;
  for (; e + 3 < hi; e += 4) {
    int s0 = esrc[e], s1 = esrc[e + 1], s2 = esrc[e + 2], s3 = esrc[e + 3];
    float n0 = norm[s0], n1 = norm[s1], n2 = norm[s2], n3 = norm[s3];
    float2 v0 = *reinterpret_cast<const float2*>(h + (size_t)s0 * N_IN + lane * 2);
    float2 v1 = *reinterpret_cast<const float2*>(h + (size_t)s1 * N_IN + lane * 2);
    float2 v2 = *reinterpret_cast<const float2*>(h + (size_t)s2 * N_IN + lane * 2);
    float2 v3 = *reinterpret_cast<const float2*>(h + (size_t)s3 * N_IN + lane * 2);
    a0.x = fmaf(v0.x, n0, a0.x); a0.y = fmaf(v0.y, n0, a0.y);
    a1.x = fmaf(v1.x, n1, a1.x); a1.y = fmaf(v1.y, n1, a1.y);
    a2.x = fmaf(v2.x, n2, a2.x); a2.y = fmaf(v2.y, n2, a2.y);
    a3.x = fmaf(v3.x, n3, a3.x); a3.y = fmaf(v3.y, n3, a3.y);
  }
  for (; e < hi; e++) {
    int s0 = esrc[e];
    float n0 = norm[s0];
    float2 v0 = *reinterpret_cast<const float2*>(h + (size_t)s0 * N_IN + lane * 2);
    a0.x = fmaf(v0.x, n0, a0.x); a0.y = fmaf(v0.y, n0, a0.y);
  }
  float rx = (a0.x + a1.x) + (a2.x + a3.x);
  float ry = (a0.y + a1.y) + (a2.y + a3.y);
  uint2 p = make_uint2(pack_hilo(rx), pack_hilo(ry));
  *reinterpret_cast<uint2*>(aggP + (size_t)node * N_IN + lane * 2) = p;
}

// ---------------- W pack: fragment-order (hi,lo) bf16 planes ----------------
__global__ void k_packW(const float* __restrict__ W, uint4* __restrict__ WH,
                        uint4* __restrict__ WL, int Ncols, int nct, int nks) {
  int g = blockIdx.x * 256 + threadIdx.x;
  if (g >= nct * nks * 64) return;
  int lane = g & 63;
  int grp = g >> 6;
  int ks = grp % nks, ct = grp / nks;
  int k0 = ks * 32 + (lane >> 4) * 8;
  int col = ct * 16 + (lane & 15);
  uint32_t hb[8], lb[8];
#pragma unroll
  for (int j = 0; j < 8; j++) {
    float w = W[(size_t)(k0 + j) * Ncols + col];
    uint32_t bits = __builtin_bit_cast(uint32_t, w);
    uint32_t hi = bits & 0xffff0000u;
    float lo = w - __builtin_bit_cast(float, hi);
    hb[j] = hi >> 16;
    lb[j] = __builtin_bit_cast(uint32_t, lo) >> 16;
  }
  WH[g] = make_uint4(hb[0] | (hb[1] << 16), hb[2] | (hb[3] << 16),
                     hb[4] | (hb[5] << 16), hb[6] | (hb[7] << 16));
  WL[g] = make_uint4(lb[0] | (lb[1] << 16), lb[2] | (lb[3] << 16),
                     lb[4] | (lb[5] << 16), lb[6] | (lb[7] << 16));
}

// ---------------- GEMM1 (split-bf16 MFMA, no LDS) ----------------
__global__ __launch_bounds__(256) void k_gemm1_mfma(
    const uint32_t* __restrict__ aggP, const uint4* __restrict__ WH,
    const uint4* __restrict__ WL, const float* __restrict__ b1,
    const float* __restrict__ norm, uint32_t* __restrict__ h1sP, int Nn) {
  const int tid = threadIdx.x;
  const int wave = tid >> 6, lane = tid & 63;
  const int row0 = blockIdx.x * 64 + wave * 16;
  const int lrow = lane & 15, lk = lane >> 4;
  int arow = row0 + lrow; if (arow >= Nn) arow = Nn - 1;

  f32x4 acc[16];
#pragma unroll
  for (int ct = 0; ct < 16; ct++) acc[ct] = f32x4{0.f, 0.f, 0.f, 0.f};

#pragma unroll
  for (int ks = 0; ks < 4; ks++) {
    const uint4* ap = reinterpret_cast<const uint4*>(aggP + (size_t)arow * N_IN + ks * 32 + lk * 8);
    uint4 p0 = ap[0], p1 = ap[1];
    uint32_t pw[8] = {p0.x, p0.y, p0.z, p0.w, p1.x, p1.y, p1.z, p1.w};
    union { ushort u[8]; bf16x8 v; } ah, al;
#pragma unroll
    for (int j = 0; j < 8; j++) { ah.u[j] = (ushort)(pw[j] >> 16); al.u[j] = (ushort)(pw[j] & 0xffffu); }
#pragma unroll
    for (int ct = 0; ct < 16; ct++) {
      union { uint4 q; bf16x8 v; } bh, bl;
      bh.q = WH[(ct * 4 + ks) * 64 + lane];
      bl.q = WL[(ct * 4 + ks) * 64 + lane];
      acc[ct] = __builtin_amdgcn_mfma_f32_16x16x32_bf16(ah.v, bh.v, acc[ct], 0, 0, 0);
      acc[ct] = __builtin_amdgcn_mfma_f32_16x16x32_bf16(ah.v, bl.v, acc[ct], 0, 0, 0);
      acc[ct] = __builtin_amdgcn_mfma_f32_16x16x32_bf16(al.v, bh.v, acc[ct], 0, 0, 0);
    }
  }

  const int colb = lane & 15, rgrp = lane >> 4;
#pragma unroll
  for (int r = 0; r < 4; r++) {
    int row = row0 + rgrp * 4 + r;
    if (row >= Nn) continue;
    float nr = norm[row];
#pragma unroll
    for (int ct = 0; ct < 16; ct++) {
      int col = ct * 16 + colb;
      float v = fmaf(acc[ct][r], nr, b1[col]);
      v = fmaxf(v, 0.f);
      v = drop_keep((uint32_t)row * (uint32_t)N_H + (uint32_t)col) ? v * 2.0f : 0.f;
      v *= nr;   // pre-apply src norm for layer 2
      h1sP[(size_t)row * N_H + col] = pack_hilo(v);
    }
  }
}

// ---------------- GEMM2 (split-bf16 MFMA): z = h1s @ W2 ----------------
__global__ __launch_bounds__(256) void k_gemm2_mfma(
    const uint32_t* __restrict__ h1sP, const uint4* __restrict__ WH,
    const uint4* __restrict__ WL, float* __restrict__ z, int Nn) {
  const int tid = threadIdx.x;
  const int wave = tid >> 6, lane = tid & 63;
  const int row0 = blockIdx.x * 64 + wave * 16;
  const int lrow = lane & 15, lk = lane >> 4;
  int arow = row0 + lrow; if (arow >= Nn) arow = Nn - 1;

  f32x4 acc[4];
#pragma unroll
  for (int ct = 0; ct < 4; ct++) acc[ct] = f32x4{0.f, 0.f, 0.f, 0.f};

#pragma unroll
  for (int ks = 0; ks < 8; ks++) {
    const uint4* ap = reinterpret_cast<const uint4*>(h1sP + (size_t)arow * N_H + ks * 32 + lk * 8);
    uint4 p0 = ap[0], p1 = ap[1];
    uint32_t pw[8] = {p0.x, p0.y, p0.z, p0.w, p1.x, p1.y, p1.z, p1.w};
    union { ushort u[8]; bf16x8 v; } ah, al;
#pragma unroll
    for (int j = 0; j < 8; j++) { ah.u[j] = (ushort)(pw[j] >> 16); al.u[j] = (ushort)(pw[j] & 0xffffu); }
#pragma unroll
    for (int ct = 0; ct < 4; ct++) {
      union { uint4 q; bf16x8 v; } bh, bl;
      bh.q = WH[(ct * 8 + ks) * 64 + lane];
      bl.q = WL[(ct * 8 + ks) * 64 + lane];
      acc[ct] = __builtin_amdgcn_mfma_f32_16x16x32_bf16(ah.v, bh.v, acc[ct], 0, 0, 0);
      acc[ct] = __builtin_amdgcn_mfma_f32_16x16x32_bf16(ah.v, bl.v, acc[ct], 0, 0, 0);
      acc[ct] = __builtin_amdgcn_mfma_f32_16x16x32_bf16(al.v, bh.v, acc[ct], 0, 0, 0);
    }
  }

  const int colb = lane & 15, rgrp = lane >> 4;
#pragma unroll
  for (int r = 0; r < 4; r++) {
    int row = row0 + rgrp * 4 + r;
    if (row >= Nn) continue;
#pragma unroll
    for (int ct = 0; ct < 4; ct++)
      z[(size_t)row * N_OUT + ct * 16 + colb] = acc[ct][r];
  }
}

// ---------------- layer-2 pull fused epilogue ----------------
__global__ __launch_bounds__(256) void k_pull2(
    const float* __restrict__ z, const float* __restrict__ norm,
    const float* __restrict__ b2, const int* __restrict__ rowptr,
    const int* __restrict__ esrc, float* __restrict__ out, int N) {
  int node = blockIdx.x * 4 + (threadIdx.x >> 6);
  if (node >= N) return;
  int lane = threadIdx.x & 63;
  int lo = rowptr[node], hi = rowptr[node + 1];
  float a0 = 0.f, a1 = 0.f, a2 = 0.f, a3 = 0.f;
  int e = lo;
  for (; e + 3 < hi; e += 4) {
    int s0 = esrc[e], s1 = esrc[e + 1], s2 = esrc[e + 2], s3 = esrc[e + 3];
    a0 += z[(size_t)s0 * N_OUT + lane];
    a1 += z[(size_t)s1 * N_OUT + lane];
    a2 += z[(size_t)s2 * N_OUT + lane];
    a3 += z[(size_t)s3 * N_OUT + lane];
  }
  for (; e < hi; e++) a0 += z[(size_t)esrc[e] * N_OUT + lane];
  out[(size_t)node * N_OUT + lane] = ((a0 + a1) + (a2 + a3)) * norm[node] + b2[lane];
}

extern "C" void kernel_launch(void* const* d_in, const int* in_sizes, int n_in,
                              void* d_out, int out_size, void* d_ws, size_t ws_size,
                              hipStream_t stream) {
  const float* h  = (const float*)d_in[0];
  const float* W1 = (const float*)d_in[1];
  const float* b1 = (const float*)d_in[2];
  const float* W2 = (const float*)d_in[3];
  const float* b2 = (const float*)d_in[4];
  const int* eidx = (const int*)d_in[5];
  const int N = in_sizes[0] / N_IN;
  const int E = in_sizes[5] / 2;
  const int NB = (N + 1023) / 1024;   // scan blocks (<= 64)

  char* ws = (char*)d_ws;
  size_t off = 0;
  auto alloc = [&](size_t bytes) { void* p = ws + off; off += (bytes + 511) & ~(size_t)511; return p; };
  int*      eflag  = (int*)alloc(sizeof(int));
  int*      deg    = (int*)alloc((size_t)N * 4);
  int*      rowptr = (int*)alloc((size_t)(N + 1) * 4);
  int*      cursor = (int*)alloc((size_t)N * 4);
  float*    norm   = (float*)alloc((size_t)N * 4);
  int*      esrc   = (int*)alloc((size_t)E * 4);
  int*      bsum   = (int*)alloc((size_t)64 * 4);
  int*      boff   = (int*)alloc((size_t)64 * 4);
  uint4*    W1H    = (uint4*)alloc((size_t)16 * 4 * 64 * 16);
  uint4*    W1L    = (uint4*)alloc((size_t)16 * 4 * 64 * 16);
  uint4*    W2H    = (uint4*)alloc((size_t)4 * 8 * 64 * 16);
  uint4*    W2L    = (uint4*)alloc((size_t)4 * 8 * 64 * 16);
  uint32_t* aggP   = (uint32_t*)alloc((size_t)N * N_IN * 4);
  uint32_t* h1sP   = (uint32_t*)alloc((size_t)N * N_H * 4);
  float*    z      = (float*)aggP;   // aggP dead after gemm1; z is 12.8 MB < 25.6 MB
  float*    out    = (float*)d_out;

  hipMemsetAsync(deg, 0, (size_t)N * 4, stream);

  // W packing is graph-independent: launch first
  k_packW<<<(16 * 4 * 64 + 255) / 256, 256, 0, stream>>>(W1, W1H, W1L, N_H, 16, 4);
  k_packW<<<(4 * 8 * 64 + 255) / 256, 256, 0, stream>>>(W2, W2H, W2L, N_OUT, 4, 8);

  k_detect<<<1, 256, 0, stream>>>(eidx, E, eflag);
  k_deg<<<(E + 255) / 256, 256, 0, stream>>>(eidx, deg, E, eflag);
  k_scanA<<<NB, 256, 0, stream>>>(deg, bsum, N);
  k_scanB<<<1, 64, 0, stream>>>(bsum, boff, rowptr + N, NB);
  k_scanC<<<NB, 256, 0, stream>>>(deg, boff, rowptr, norm, cursor, N);
  k_fill<<<(E + 255) / 256, 256, 0, stream>>>(eidx, cursor, esrc, E, eflag);
  k_sortlds<<<(N + 255) / 256, 256, 0, stream>>>(esrc, rowptr, N);

  k_pull1<<<(N + 3) / 4, 256, 0, stream>>>(h, norm, rowptr, esrc, aggP, N);

  k_gemm1_mfma<<<(N + 63) / 64, 256, 0, stream>>>(aggP, W1H, W1L, b1, norm, h1sP, N);
  k_gemm2_mfma<<<(N + 63) / 64, 256, 0, stream>>>(h1sP, W2H, W2L, z, N);

  k_pull2<<<(N + 3) / 4, 256, 0, stream>>>(z, norm, b2, rowptr, esrc, out, N);
}